// Round 4
// baseline (105.381 us; speedup 1.0000x reference)
//
#include <hip/hip_runtime.h>
#include <hip/hip_bf16.h>

typedef short short4v __attribute__((ext_vector_type(4)));
typedef short short8v __attribute__((ext_vector_type(8)));
typedef float float4v __attribute__((ext_vector_type(4)));
typedef __bf16 bf16x8 __attribute__((ext_vector_type(8)));

typedef __attribute__((address_space(1))) const unsigned int g_uint;
typedef __attribute__((address_space(3))) unsigned int lds_uint;

__device__ __forceinline__ unsigned short f2bf(float f) {
    union { float f; unsigned int i; } t;
    t.f = f;
    unsigned int u = t.i;
    u += 0x7fffu + ((u >> 16) & 1u);   // round-to-nearest-even
    return (unsigned short)(u >> 16);
}

__device__ __forceinline__ short bfcast(float f) {
    __bf16 h = (__bf16)f;               // native cvt (compiler fuses pairs into v_cvt_pk_bf16_f32)
    return __builtin_bit_cast(short, h);
}

// v_exp_f32 computes 2^x; s_nop covers the trans->valu wait state
__device__ __forceinline__ float fast_exp2(float x) {
    float r;
    asm("v_exp_f32 %0, %1\n\ts_nop 0" : "=v"(r) : "v"(x));
    return r;
}

// async global->LDS, 16B per lane; lds dest is wave-uniform base + lane*16
__device__ __forceinline__ void gload_lds16(const unsigned short* g, unsigned short* l) {
    __builtin_amdgcn_global_load_lds((g_uint*)g, (lds_uint*)l, 16, 0, 0);
}

// read 8 contiguous bf16 (b128) from a swizzled [64][64] u16 LDS tile:
// element (row, 8*slot + i) lives at u16 offset row*64 + ((slot ^ (row&7))<<3) + i
__device__ __forceinline__ bf16x8 frag128(const unsigned short* t, int row, int slot) {
    return *reinterpret_cast<const bf16x8*>(
        reinterpret_cast<const char*>(t) + row * 128 + (((slot ^ (row & 7)) << 4)));
}

__device__ __forceinline__ float4v mfma32(bf16x8 a, bf16x8 b, float4v c) {
    return __builtin_amdgcn_mfma_f32_16x16x32_bf16(a, b, c, 0, 0, 0);
}

// ---------------------------------------------------------------------------
// Kernel 0: weights f32 -> bf16
// ---------------------------------------------------------------------------
__global__ __launch_bounds__(256) void prep_kernel(const float* __restrict__ wq,
                                                   const float* __restrict__ wo,
                                                   unsigned short* __restrict__ wqb,
                                                   unsigned short* __restrict__ wob) {
    int i = blockIdx.x * 256 + threadIdx.x;   // 262144 total
    if (i < 196608) wqb[i] = f2bf(wq[i]);
    else            wob[i - 196608] = f2bf(wo[i - 196608]);
}

// ---------------------------------------------------------------------------
// Kernel 1: channel LayerNorm.  x[b][c=256][pix] f32 -> xn_T[b][pix][c] bf16.
// ---------------------------------------------------------------------------
__global__ __launch_bounds__(256) void ln_kernel(const float* __restrict__ x,
                                                 const float* __restrict__ g,
                                                 unsigned short* __restrict__ xnT) {
    __shared__ float red[2][4][64];
    const int tid = threadIdx.x;
    const int p = tid & 63, cg = tid >> 6;
    const int b = blockIdx.y;
    const int pix = blockIdx.x * 64 + p;
    const float* xb = x + ((size_t)b << 18) + pix;

    float v[64];
    float s = 0.f, q = 0.f;
    #pragma unroll
    for (int cc = 0; cc < 64; ++cc) {
        v[cc] = xb[(cg * 64 + cc) << 10];
        s += v[cc]; q += v[cc] * v[cc];
    }
    red[0][cg][p] = s; red[1][cg][p] = q;
    __syncthreads();
    float ts = red[0][0][p] + red[0][1][p] + red[0][2][p] + red[0][3][p];
    float tq = red[1][0][p] + red[1][1][p] + red[1][2][p] + red[1][3][p];
    float mean = ts * (1.f / 256.f);
    float var  = tq * (1.f / 256.f) - mean * mean;
    float rstd = rsqrtf(var + 1e-5f);
    float bias = -mean * rstd;

    unsigned short* dst = xnT + (((size_t)b << 10) + pix) * 256 + cg * 64;
    #pragma unroll
    for (int cc = 0; cc < 64; cc += 8) {
        union { uint4 u; unsigned short s[8]; } pk;
        #pragma unroll
        for (int j = 0; j < 8; ++j)
            pk.s[j] = f2bf(fmaf(v[cc + j], rstd, bias) * g[cg * 64 + cc + j]);
        *reinterpret_cast<uint4*>(dst + cc) = pk.u;
    }
}

// ---------------------------------------------------------------------------
// Kernel 2: QKV GEMM, fused L2-norm + attention-ready layouts.
// 1D grid 3072, XCD-swizzled so all 12 m-blocks of one X-tile share an XCD.
// m<4: qhat[bh][pix][d] (q * rn * 8*log2e);  m 4..7: khat[bh][j][d] plain;
// m>=8: vperm[bh][tile][d][colperm(j)] (16B-fragment-ready for PV).
// ---------------------------------------------------------------------------
__global__ __launch_bounds__(256) void qkv_gemm(const unsigned short* __restrict__ xnT,
                                                const unsigned short* __restrict__ wqkv,
                                                unsigned short* __restrict__ qhat,
                                                unsigned short* __restrict__ khat,
                                                unsigned short* __restrict__ vperm) {
    __shared__ __align__(16) unsigned short sW[8192];
    __shared__ __align__(16) unsigned short sX[8192];
    const int tid = threadIdx.x, lane = tid & 63, w = tid >> 6;
    const int l16 = lane & 15, g = lane >> 4;
    const int id = blockIdx.x;
    const int xcd = id & 7, sIdx = id >> 3;
    const int m = sIdx % 12, tq = sIdx / 12;
    const int t = xcd + (tq << 3);            // 0..255 X-tile index
    const int pb = t & 15, b = t >> 4;

    const unsigned short* Wbase = wqkv + m * 64 * 256;
    const unsigned short* Xbase = xnT + (((size_t)b << 10) + pb * 64) * 256;

    const int srow = (lane >> 3);
    const int sslot = lane & 7;

    auto stage = [&](int buf, int k0) {
        #pragma unroll
        for (int ii = 0; ii < 2; ++ii) {
            int inst = w + 4 * ii;
            int row = inst * 8 + srow;
            int src = row * 256 + k0 + 8 * (sslot ^ (row & 7));
            gload_lds16(Wbase + src, &sW[buf * 4096 + inst * 512]);
            gload_lds16(Xbase + src, &sX[buf * 4096 + inst * 512]);
        }
    };

    float4v acc[4] = {{0,0,0,0},{0,0,0,0},{0,0,0,0},{0,0,0,0}};
    const bool qk = (m < 8);

    stage(0, 0);
    __syncthreads();
    for (int ks = 0; ks < 4; ++ks) {
        if (ks < 3) stage((ks + 1) & 1, (ks + 1) * 64);
        const unsigned short* Wt = &sW[(ks & 1) * 4096];
        const unsigned short* Xt = &sX[(ks & 1) * 4096];
        #pragma unroll
        for (int kk = 0; kk < 2; ++kk) {
            bf16x8 aF = frag128(qk ? Xt : Wt, 16 * w + l16, 4 * kk + g);
            #pragma unroll
            for (int jt = 0; jt < 4; ++jt) {
                bf16x8 bF = frag128(qk ? Wt : Xt, 16 * jt + l16, 4 * kk + g);
                acc[jt] = mfma32(aF, bF, acc[jt]);
            }
        }
        __syncthreads();
    }

    if (qk) {
        // D[pix = pb*64 + 16w + 4g + r][d(head) = 16jt + l16]; l2-norm over d
        float rn[4];
        #pragma unroll
        for (int r = 0; r < 4; ++r) {
            float s = acc[0][r]*acc[0][r] + acc[1][r]*acc[1][r]
                    + acc[2][r]*acc[2][r] + acc[3][r]*acc[3][r];
            s += __shfl_xor(s, 1, 64);
            s += __shfl_xor(s, 2, 64);
            s += __shfl_xor(s, 4, 64);
            s += __shfl_xor(s, 8, 64);
            rn[r] = rsqrtf(fmaxf(s, 1e-24f));
        }
        int h = m & 3;
        int bh = b * 4 + h;
        if (m < 4) {
            // fold 8*log2(e) so attention can use p = exp2(st) with no bias
            unsigned short* qb = qhat + ((size_t)bh << 16) + (size_t)(pb * 64 + 16 * w) * 64;
            #pragma unroll
            for (int jt = 0; jt < 4; ++jt)
                #pragma unroll
                for (int r = 0; r < 4; ++r)
                    qb[(4 * g + r) * 64 + 16 * jt + l16] =
                        f2bf(acc[jt][r] * (rn[r] * 11.541560327111707f));
        } else {
            unsigned short* kb = khat + ((size_t)bh << 16) + (size_t)pb * 4096;
            #pragma unroll
            for (int jt = 0; jt < 4; ++jt)
                #pragma unroll
                for (int r = 0; r < 4; ++r)
                    kb[(16 * w + 4 * g + r) * 64 + 16 * jt + l16] = f2bf(acc[jt][r] * rn[r]);
        }
    } else {
        // D[d = 16w + 4g + r][j = 16jt + l16] -> vperm[d][ (l16>>2)*16 + jt*4 + (l16&3) ]
        int bh = b * 4 + (m - 8);
        unsigned short* vb = vperm + ((size_t)bh << 16) + (size_t)pb * 4096;
        const int colbase = (l16 >> 2) * 16 + (l16 & 3);
        #pragma unroll
        for (int jt = 0; jt < 4; ++jt)
            #pragma unroll
            for (int r = 0; r < 4; ++r) {
                int d = 16 * w + 4 * g + r;
                vb[d * 64 + colbase + jt * 4] = f2bf(acc[jt][r]);
            }
    }
}

// ---------------------------------------------------------------------------
// Kernel 3: flash attention, register-pipelined, LDS-free main loop.
// 1D grid 512 XCD-swizzled (all 8 q-blocks of a (b,h) on one XCD).
// K/V fragments for tile t+1 prefetched into a register double-buffer at the
// top of tile t (issue-early / use-late; ~full tile of compute covers L2 lat).
// Fixed-max softmax: q pre-scaled by 8*log2e, p = exp2(st) (bias cancels).
// No barriers in the loop.
// ---------------------------------------------------------------------------
__global__ __launch_bounds__(256) void attn_kernel(const unsigned short* __restrict__ qhat,
                                                   const unsigned short* __restrict__ khat,
                                                   const unsigned short* __restrict__ vperm,
                                                   unsigned short* __restrict__ oT) {
    __shared__ __align__(16) unsigned short OL[128 * 72];
    const int tid = threadIdx.x, lane = tid & 63, w = tid >> 6;
    const int l16 = lane & 15, g = lane >> 4;
    const int id = blockIdx.x;
    const int sIdx = id >> 3;
    const int bh = (id & 7) * 8 + (sIdx >> 3);
    const int qb = sIdx & 7;
    const int b = bh >> 2, h = bh & 3;

    const unsigned short* Qg = qhat + ((size_t)bh << 16) + (size_t)(qb * 128) * 64;
    const unsigned short* Kg = khat + ((size_t)bh << 16);
    const unsigned short* Vg = vperm + ((size_t)bh << 16);

    // Q fragments (B-operand of K=32 mfma): col i = l16, k = d = 32*ds + 8*g + [0..8)
    bf16x8 bq[2][2];
    #pragma unroll
    for (int it = 0; it < 2; ++it)
        #pragma unroll
        for (int ds = 0; ds < 2; ++ds)
            bq[it][ds] = *reinterpret_cast<const bf16x8*>(
                Qg + (32 * w + 16 * it + l16) * 64 + 32 * ds + 8 * g);

    float lsum[2] = {0.f, 0.f};
    float4v oacc[2][4] = {};

    // register double-buffers for K and V fragments (named, statically indexed)
    bf16x8 kA[2][4], kB[2][4];
    short8v vA[4][2], vB[4][2];

    auto loadKV = [&](bf16x8 (&kd)[2][4], short8v (&vd)[4][2], int t) {
        const unsigned short* kt = Kg + t * 4096;
        const unsigned short* vt = Vg + t * 4096;
        #pragma unroll
        for (int ds = 0; ds < 2; ++ds)
            #pragma unroll
            for (int jt = 0; jt < 4; ++jt)
                kd[ds][jt] = *reinterpret_cast<const bf16x8*>(
                    kt + (16 * jt + l16) * 64 + 32 * ds + 8 * g);
        #pragma unroll
        for (int dt = 0; dt < 4; ++dt)
            #pragma unroll
            for (int q = 0; q < 2; ++q)
                vd[dt][q] = *reinterpret_cast<const short8v*>(
                    vt + (16 * dt + l16) * 64 + 16 * g + 8 * q);
    };

    auto tile = [&](bf16x8 (&kc)[2][4], short8v (&vc)[4][2],
                    bf16x8 (&kn)[2][4], short8v (&vn)[4][2], int nt) {
        // prefetch next tile's K,V (waits land before their use next tile)
        loadKV(kn, vn, nt);

        // S^T[j][i] = sum_d K[j][d] Q^T[d][i]
        float4v st[2][4] = {};
        __builtin_amdgcn_s_setprio(1);
        #pragma unroll
        for (int ds = 0; ds < 2; ++ds)
            #pragma unroll
            for (int jt = 0; jt < 4; ++jt)
                #pragma unroll
                for (int it = 0; it < 2; ++it)
                    st[it][jt] = mfma32(kc[ds][jt], bq[it][ds], st[it][jt]);
        __builtin_amdgcn_s_setprio(0);

        // fixed-max softmax: p = exp2(st); no max tracking, no rescale
        short4v pf[2][4];
        #pragma unroll
        for (int it = 0; it < 2; ++it) {
            #pragma unroll
            for (int jt = 0; jt < 4; ++jt) {
                float p0 = fast_exp2(st[it][jt][0]);
                float p1 = fast_exp2(st[it][jt][1]);
                float p2 = fast_exp2(st[it][jt][2]);
                float p3 = fast_exp2(st[it][jt][3]);
                lsum[it] += (p0 + p1) + (p2 + p3);
                short4v tt;
                tt[0] = bfcast(p0); tt[1] = bfcast(p1);
                tt[2] = bfcast(p2); tt[3] = bfcast(p3);
                pf[it][jt] = tt;
            }
        }

        // O^T[d][i] += V^T[d][j] P^T[j][i]
        __builtin_amdgcn_s_setprio(1);
        #pragma unroll
        for (int dt = 0; dt < 4; ++dt)
            #pragma unroll
            for (int q = 0; q < 2; ++q) {
                short4v lo = __builtin_shufflevector(vc[dt][q], vc[dt][q], 0, 1, 2, 3);
                short4v hi = __builtin_shufflevector(vc[dt][q], vc[dt][q], 4, 5, 6, 7);
                #pragma unroll
                for (int it = 0; it < 2; ++it) {
                    oacc[it][dt] = __builtin_amdgcn_mfma_f32_16x16x16bf16_1k(
                        lo, pf[it][2 * q], oacc[it][dt], 0, 0, 0);
                    oacc[it][dt] = __builtin_amdgcn_mfma_f32_16x16x16bf16_1k(
                        hi, pf[it][2 * q + 1], oacc[it][dt], 0, 0, 0);
                }
            }
        __builtin_amdgcn_s_setprio(0);
    };

    loadKV(kA, vA, 0);
    for (int t = 0; t < 16; t += 2) {
        tile(kA, vA, kB, vB, t + 1);          // uses buf A, prefetches t+1 into B
        tile(kB, vB, kA, vA, (t + 2) & 15);   // uses buf B, prefetches t+2 into A
    }

    // single cross-lane reduction of the softmax denominator
    #pragma unroll
    for (int it = 0; it < 2; ++it) {
        lsum[it] += __shfl_xor(lsum[it], 16, 64);
        lsum[it] += __shfl_xor(lsum[it], 32, 64);
    }

    // transpose O through LDS -> O_T[pix][h*64+d], 16B stores
    #pragma unroll
    for (int it = 0; it < 2; ++it) {
        float inv = 1.f / lsum[it];
        int irow = 32 * w + 16 * it + l16;
        #pragma unroll
        for (int dt = 0; dt < 4; ++dt)
            #pragma unroll
            for (int r = 0; r < 4; ++r)
                OL[irow * 72 + 16 * dt + 4 * g + r] = f2bf(oacc[it][dt][r] * inv);
    }
    __syncthreads();
    {
        int row = tid >> 1, half = tid & 1;
        unsigned short* dst = oT + (((size_t)b << 10) + qb * 128 + row) * 256 + h * 64 + half * 32;
        const unsigned short* src = OL + row * 72 + half * 32;
        #pragma unroll
        for (int q = 0; q < 4; ++q)
            *reinterpret_cast<uint4*>(dst + q * 8) =
                *reinterpret_cast<const uint4*>(src + q * 8);
    }
}

// ---------------------------------------------------------------------------
// Kernel 4: out projection + residual.  1D grid 1024, XCD-swizzled.
// ---------------------------------------------------------------------------
__global__ __launch_bounds__(256) void out_gemm(const unsigned short* __restrict__ oT,
                                                const unsigned short* __restrict__ wout,
                                                const float* __restrict__ x,
                                                float* __restrict__ out) {
    __shared__ __align__(16) unsigned short sW[8192];
    __shared__ __align__(16) unsigned short sX[8192];
    const int tid = threadIdx.x, lane = tid & 63, w = tid >> 6;
    const int l16 = lane & 15, g = lane >> 4;
    const int id = blockIdx.x;
    const int xcd = id & 7, sIdx = id >> 3;   // sIdx 0..127
    const int m = sIdx & 3, tq = sIdx >> 2;
    const int t = xcd + (tq << 3);
    const int pb = t & 15, b = t >> 4;

    const unsigned short* Wbase = wout + m * 64 * 256;
    const unsigned short* Xbase = oT + (((size_t)b << 10) + pb * 64) * 256;

    const int srow = (lane >> 3);
    const int sslot = lane & 7;

    auto stage = [&](int buf, int k0) {
        #pragma unroll
        for (int ii = 0; ii < 2; ++ii) {
            int inst = w + 4 * ii;
            int row = inst * 8 + srow;
            int src = row * 256 + k0 + 8 * (sslot ^ (row & 7));
            gload_lds16(Wbase + src, &sW[buf * 4096 + inst * 512]);
            gload_lds16(Xbase + src, &sX[buf * 4096 + inst * 512]);
        }
    };

    float4v acc[4] = {{0,0,0,0},{0,0,0,0},{0,0,0,0},{0,0,0,0}};
    stage(0, 0);
    __syncthreads();
    for (int ks = 0; ks < 4; ++ks) {
        if (ks < 3) stage((ks + 1) & 1, (ks + 1) * 64);
        const unsigned short* Wt = &sW[(ks & 1) * 4096];
        const unsigned short* Xt = &sX[(ks & 1) * 4096];
        #pragma unroll
        for (int kk = 0; kk < 2; ++kk) {
            bf16x8 aF = frag128(Wt, 16 * w + l16, 4 * kk + g);
            #pragma unroll
            for (int jt = 0; jt < 4; ++jt) {
                bf16x8 bF = frag128(Xt, 16 * jt + l16, 4 * kk + g);
                acc[jt] = mfma32(aF, bF, acc[jt]);
            }
        }
        __syncthreads();
    }

    #pragma unroll
    for (int jt = 0; jt < 4; ++jt)
        #pragma unroll
        for (int r = 0; r < 4; ++r) {
            size_t idx = ((size_t)b << 18) + (size_t)(m * 64 + 16 * w + 4 * g + r) * 1024
                       + pb * 64 + 16 * jt + l16;
            out[idx] = acc[jt][r] + x[idx];
        }
}

// ---------------------------------------------------------------------------
extern "C" void kernel_launch(void* const* d_in, const int* in_sizes, int n_in,
                              void* d_out, int out_size, void* d_ws, size_t ws_size,
                              hipStream_t stream) {
    const float* x  = (const float*)d_in[0];
    const float* g  = (const float*)d_in[1];
    const float* wq = (const float*)d_in[2];
    const float* wo = (const float*)d_in[3];
    float* out = (float*)d_out;

    char* ws = (char*)d_ws;
    // ws layout:
    //   [0, 8.4MB)        xn_T bf16 [16][1024][256]; reused as O_T after qkv_gemm
    //   [8.4, 16.8MB)     qhat bf16 [bh=64][1024][64]  (scaled by 8*log2e)
    //   [16.8, 25.2MB)    khat bf16 [bh=64][1024][64]
    //   [25.2, 33.6MB)    vperm bf16 [bh=64][16][64][64-permuted]
    //   [33.6MB, ...)     w_qkv bf16, w_out bf16
    unsigned short* xnT   = (unsigned short*)(ws);
    unsigned short* qhat  = (unsigned short*)(ws + 8388608);
    unsigned short* khat  = (unsigned short*)(ws + 16777216);
    unsigned short* vperm = (unsigned short*)(ws + 25165824);
    unsigned short* wqb   = (unsigned short*)(ws + 33554432);
    unsigned short* wob   = (unsigned short*)(ws + 33947648);
    unsigned short* oT    = xnT;   // reuse

    prep_kernel<<<1024, 256, 0, stream>>>(wq, wo, wqb, wob);
    ln_kernel<<<dim3(16, 16), 256, 0, stream>>>(x, g, xnT);
    qkv_gemm<<<3072, 256, 0, stream>>>(xnT, wqb, qhat, khat, vperm);
    attn_kernel<<<512, 256, 0, stream>>>(qhat, khat, vperm, oT);
    out_gemm<<<1024, 256, 0, stream>>>(oT, wob, x, out);
}

// Round 5
// 104.152 us; speedup vs baseline: 1.0118x; 1.0118x over previous
//
#include <hip/hip_runtime.h>
#include <hip/hip_bf16.h>

typedef short short4v __attribute__((ext_vector_type(4)));
typedef short short8v __attribute__((ext_vector_type(8)));
typedef float float4v __attribute__((ext_vector_type(4)));
typedef __bf16 bf16x8 __attribute__((ext_vector_type(8)));

typedef __attribute__((address_space(1))) const unsigned int g_uint;
typedef __attribute__((address_space(3))) unsigned int lds_uint;

__device__ __forceinline__ unsigned short f2bf(float f) {
    union { float f; unsigned int i; } t;
    t.f = f;
    unsigned int u = t.i;
    u += 0x7fffu + ((u >> 16) & 1u);   // round-to-nearest-even
    return (unsigned short)(u >> 16);
}

__device__ __forceinline__ short bfcast(float f) {
    __bf16 h = (__bf16)f;               // native cvt (compiler fuses pairs into v_cvt_pk_bf16_f32)
    return __builtin_bit_cast(short, h);
}

// v_exp_f32 computes 2^x; s_nop covers the trans->valu wait state
__device__ __forceinline__ float fast_exp2(float x) {
    float r;
    asm("v_exp_f32 %0, %1\n\ts_nop 0" : "=v"(r) : "v"(x));
    return r;
}

// async global->LDS, 16B per lane; lds dest is wave-uniform base + lane*16
__device__ __forceinline__ void gload_lds16(const unsigned short* g, unsigned short* l) {
    __builtin_amdgcn_global_load_lds((g_uint*)g, (lds_uint*)l, 16, 0, 0);
}

// read 8 contiguous bf16 (b128) from a swizzled [64][64] u16 LDS tile:
// element (row, 8*slot + i) lives at u16 offset row*64 + ((slot ^ (row&7))<<3) + i
__device__ __forceinline__ bf16x8 frag128(const unsigned short* t, int row, int slot) {
    return *reinterpret_cast<const bf16x8*>(
        reinterpret_cast<const char*>(t) + row * 128 + (((slot ^ (row & 7)) << 4)));
}

__device__ __forceinline__ float4v mfma32(bf16x8 a, bf16x8 b, float4v c) {
    return __builtin_amdgcn_mfma_f32_16x16x32_bf16(a, b, c, 0, 0, 0);
}

// ---------------------------------------------------------------------------
// Kernel 0: weights f32 -> bf16
// ---------------------------------------------------------------------------
__global__ __launch_bounds__(256) void prep_kernel(const float* __restrict__ wq,
                                                   const float* __restrict__ wo,
                                                   unsigned short* __restrict__ wqb,
                                                   unsigned short* __restrict__ wob) {
    int i = blockIdx.x * 256 + threadIdx.x;   // 262144 total
    if (i < 196608) wqb[i] = f2bf(wq[i]);
    else            wob[i - 196608] = f2bf(wo[i - 196608]);
}

// ---------------------------------------------------------------------------
// Kernel 1: channel LayerNorm.  x[b][c=256][pix] f32 -> xn_T[b][pix][c] bf16.
// ---------------------------------------------------------------------------
__global__ __launch_bounds__(256) void ln_kernel(const float* __restrict__ x,
                                                 const float* __restrict__ g,
                                                 unsigned short* __restrict__ xnT) {
    __shared__ float red[2][4][64];
    const int tid = threadIdx.x;
    const int p = tid & 63, cg = tid >> 6;
    const int b = blockIdx.y;
    const int pix = blockIdx.x * 64 + p;
    const float* xb = x + ((size_t)b << 18) + pix;

    float v[64];
    float s = 0.f, q = 0.f;
    #pragma unroll
    for (int cc = 0; cc < 64; ++cc) {
        v[cc] = xb[(cg * 64 + cc) << 10];
        s += v[cc]; q += v[cc] * v[cc];
    }
    red[0][cg][p] = s; red[1][cg][p] = q;
    __syncthreads();
    float ts = red[0][0][p] + red[0][1][p] + red[0][2][p] + red[0][3][p];
    float tq = red[1][0][p] + red[1][1][p] + red[1][2][p] + red[1][3][p];
    float mean = ts * (1.f / 256.f);
    float var  = tq * (1.f / 256.f) - mean * mean;
    float rstd = rsqrtf(var + 1e-5f);
    float bias = -mean * rstd;

    unsigned short* dst = xnT + (((size_t)b << 10) + pix) * 256 + cg * 64;
    #pragma unroll
    for (int cc = 0; cc < 64; cc += 8) {
        union { uint4 u; unsigned short s[8]; } pk;
        #pragma unroll
        for (int j = 0; j < 8; ++j)
            pk.s[j] = f2bf(fmaf(v[cc + j], rstd, bias) * g[cg * 64 + cc + j]);
        *reinterpret_cast<uint4*>(dst + cc) = pk.u;
    }
}

// ---------------------------------------------------------------------------
// Kernel 2: QKV GEMM, fused L2-norm + attention-ready layouts.
// 1D grid 3072, XCD-swizzled so all 12 m-blocks of one X-tile share an XCD.
// m<4: qhat[bh][pix][d] (q * rn * 8*log2e);  m 4..7: khat[bh][j][d] plain;
// m>=8: vperm[bh][tile][d][colperm(j)] (16B-fragment-ready for PV).
// ---------------------------------------------------------------------------
__global__ __launch_bounds__(256) void qkv_gemm(const unsigned short* __restrict__ xnT,
                                                const unsigned short* __restrict__ wqkv,
                                                unsigned short* __restrict__ qhat,
                                                unsigned short* __restrict__ khat,
                                                unsigned short* __restrict__ vperm) {
    __shared__ __align__(16) unsigned short sW[8192];
    __shared__ __align__(16) unsigned short sX[8192];
    const int tid = threadIdx.x, lane = tid & 63, w = tid >> 6;
    const int l16 = lane & 15, g = lane >> 4;
    const int id = blockIdx.x;
    const int xcd = id & 7, sIdx = id >> 3;
    const int m = sIdx % 12, tq = sIdx / 12;
    const int t = xcd + (tq << 3);            // 0..255 X-tile index
    const int pb = t & 15, b = t >> 4;

    const unsigned short* Wbase = wqkv + m * 64 * 256;
    const unsigned short* Xbase = xnT + (((size_t)b << 10) + pb * 64) * 256;

    const int srow = (lane >> 3);
    const int sslot = lane & 7;

    auto stage = [&](int buf, int k0) {
        #pragma unroll
        for (int ii = 0; ii < 2; ++ii) {
            int inst = w + 4 * ii;
            int row = inst * 8 + srow;
            int src = row * 256 + k0 + 8 * (sslot ^ (row & 7));
            gload_lds16(Wbase + src, &sW[buf * 4096 + inst * 512]);
            gload_lds16(Xbase + src, &sX[buf * 4096 + inst * 512]);
        }
    };

    float4v acc[4] = {{0,0,0,0},{0,0,0,0},{0,0,0,0},{0,0,0,0}};
    const bool qk = (m < 8);

    stage(0, 0);
    __syncthreads();
    for (int ks = 0; ks < 4; ++ks) {
        if (ks < 3) stage((ks + 1) & 1, (ks + 1) * 64);
        const unsigned short* Wt = &sW[(ks & 1) * 4096];
        const unsigned short* Xt = &sX[(ks & 1) * 4096];
        #pragma unroll
        for (int kk = 0; kk < 2; ++kk) {
            bf16x8 aF = frag128(qk ? Xt : Wt, 16 * w + l16, 4 * kk + g);
            #pragma unroll
            for (int jt = 0; jt < 4; ++jt) {
                bf16x8 bF = frag128(qk ? Wt : Xt, 16 * jt + l16, 4 * kk + g);
                acc[jt] = mfma32(aF, bF, acc[jt]);
            }
        }
        __syncthreads();
    }

    if (qk) {
        // D[pix = pb*64 + 16w + 4g + r][d(head) = 16jt + l16]; l2-norm over d
        float rn[4];
        #pragma unroll
        for (int r = 0; r < 4; ++r) {
            float s = acc[0][r]*acc[0][r] + acc[1][r]*acc[1][r]
                    + acc[2][r]*acc[2][r] + acc[3][r]*acc[3][r];
            s += __shfl_xor(s, 1, 64);
            s += __shfl_xor(s, 2, 64);
            s += __shfl_xor(s, 4, 64);
            s += __shfl_xor(s, 8, 64);
            rn[r] = rsqrtf(fmaxf(s, 1e-24f));
        }
        int h = m & 3;
        int bh = b * 4 + h;
        if (m < 4) {
            // fold 8*log2(e) so attention can use p = exp2(st) with no bias
            unsigned short* qb = qhat + ((size_t)bh << 16) + (size_t)(pb * 64 + 16 * w) * 64;
            #pragma unroll
            for (int jt = 0; jt < 4; ++jt)
                #pragma unroll
                for (int r = 0; r < 4; ++r)
                    qb[(4 * g + r) * 64 + 16 * jt + l16] =
                        f2bf(acc[jt][r] * (rn[r] * 11.541560327111707f));
        } else {
            unsigned short* kb = khat + ((size_t)bh << 16) + (size_t)pb * 4096;
            #pragma unroll
            for (int jt = 0; jt < 4; ++jt)
                #pragma unroll
                for (int r = 0; r < 4; ++r)
                    kb[(16 * w + 4 * g + r) * 64 + 16 * jt + l16] = f2bf(acc[jt][r] * rn[r]);
        }
    } else {
        // D[d = 16w + 4g + r][j = 16jt + l16] -> vperm[d][ (l16>>2)*16 + jt*4 + (l16&3) ]
        int bh = b * 4 + (m - 8);
        unsigned short* vb = vperm + ((size_t)bh << 16) + (size_t)pb * 4096;
        const int colbase = (l16 >> 2) * 16 + (l16 & 3);
        #pragma unroll
        for (int jt = 0; jt < 4; ++jt)
            #pragma unroll
            for (int r = 0; r < 4; ++r) {
                int d = 16 * w + 4 * g + r;
                vb[d * 64 + colbase + jt * 4] = f2bf(acc[jt][r]);
            }
    }
}

// ---------------------------------------------------------------------------
// Kernel 3: flash attention, 8 waves/block (512 thr), j-split TLP.
// grid 512, XCD-swizzled.  Waves 0-3 process j-tiles 0-7, waves 4-7 tiles
// 8-15, for the same 128 queries.  Fixed-max softmax (q pre-scaled by
// 8*log2e, p = exp2(st)) makes partial (oacc, lsum) exactly additive, so the
// two j-halves combine through LDS with one barrier pair.  No in-loop
// barriers; K/V fragments read straight from L2-resident pre-laid-out global.
// ---------------------------------------------------------------------------
__global__ __launch_bounds__(512) void attn_kernel(const unsigned short* __restrict__ qhat,
                                                   const unsigned short* __restrict__ khat,
                                                   const unsigned short* __restrict__ vperm,
                                                   unsigned short* __restrict__ oT) {
    __shared__ __align__(16) float OLf[128 * 68];          // f32 partial O [q][d+pad]
    __shared__ float lsumS[128];
    __shared__ __align__(16) unsigned short OLb[128 * 72]; // final bf16 [q][d+pad]
    const int tid = threadIdx.x, lane = tid & 63, w = tid >> 6;
    const int wi = w & 3, wg = w >> 2;        // i-quarter, j-half
    const int l16 = lane & 15, g = lane >> 4;
    const int id = blockIdx.x;
    const int sIdx = id >> 3;
    const int bh = (id & 7) * 8 + (sIdx >> 3);
    const int qb = sIdx & 7;
    const int b = bh >> 2, h = bh & 3;

    const unsigned short* Qg = qhat + ((size_t)bh << 16) + (size_t)(qb * 128) * 64;
    const unsigned short* Kg = khat + ((size_t)bh << 16);
    const unsigned short* Vg = vperm + ((size_t)bh << 16);

    // Q fragments (B-operand of K=32 mfma): col i = 32*wi + 16*it + l16
    bf16x8 bq[2][2];
    #pragma unroll
    for (int it = 0; it < 2; ++it)
        #pragma unroll
        for (int ds = 0; ds < 2; ++ds)
            bq[it][ds] = *reinterpret_cast<const bf16x8*>(
                Qg + (32 * wi + 16 * it + l16) * 64 + 32 * ds + 8 * g);

    float lsum[2] = {0.f, 0.f};
    float4v oacc[2][4] = {};

    const int t0 = wg * 8;
    for (int tt = 0; tt < 8; ++tt) {
        const int t = t0 + tt;
        const unsigned short* kt = Kg + t * 4096;
        const unsigned short* vt = Vg + t * 4096;

        // S^T[j][i] = sum_d K[j][d] Q^T[d][i]
        float4v st[2][4] = {};
        #pragma unroll
        for (int ds = 0; ds < 2; ++ds) {
            bf16x8 ak[4];
            #pragma unroll
            for (int jt = 0; jt < 4; ++jt)
                ak[jt] = *reinterpret_cast<const bf16x8*>(
                    kt + (16 * jt + l16) * 64 + 32 * ds + 8 * g);
            __builtin_amdgcn_s_setprio(1);
            #pragma unroll
            for (int jt = 0; jt < 4; ++jt)
                #pragma unroll
                for (int it = 0; it < 2; ++it)
                    st[it][jt] = mfma32(ak[jt], bq[it][ds], st[it][jt]);
            __builtin_amdgcn_s_setprio(0);
        }

        // issue V fragment loads early; softmax VALU hides their latency
        short8v vv[4][2];
        #pragma unroll
        for (int dt = 0; dt < 4; ++dt)
            #pragma unroll
            for (int q = 0; q < 2; ++q)
                vv[dt][q] = *reinterpret_cast<const short8v*>(
                    vt + (16 * dt + l16) * 64 + 16 * g + 8 * q);

        // fixed-max softmax: p = exp2(st); no max tracking, no rescale
        short4v pf[2][4];
        #pragma unroll
        for (int it = 0; it < 2; ++it) {
            #pragma unroll
            for (int jt = 0; jt < 4; ++jt) {
                float p0 = fast_exp2(st[it][jt][0]);
                float p1 = fast_exp2(st[it][jt][1]);
                float p2 = fast_exp2(st[it][jt][2]);
                float p3 = fast_exp2(st[it][jt][3]);
                lsum[it] += (p0 + p1) + (p2 + p3);
                short4v tt2;
                tt2[0] = bfcast(p0); tt2[1] = bfcast(p1);
                tt2[2] = bfcast(p2); tt2[3] = bfcast(p3);
                pf[it][jt] = tt2;
            }
        }

        // O^T[d][i] += V^T[d][j] P^T[j][i]
        __builtin_amdgcn_s_setprio(1);
        #pragma unroll
        for (int dt = 0; dt < 4; ++dt)
            #pragma unroll
            for (int q = 0; q < 2; ++q) {
                short4v lo = __builtin_shufflevector(vv[dt][q], vv[dt][q], 0, 1, 2, 3);
                short4v hi = __builtin_shufflevector(vv[dt][q], vv[dt][q], 4, 5, 6, 7);
                #pragma unroll
                for (int it = 0; it < 2; ++it) {
                    oacc[it][dt] = __builtin_amdgcn_mfma_f32_16x16x16bf16_1k(
                        lo, pf[it][2 * q], oacc[it][dt], 0, 0, 0);
                    oacc[it][dt] = __builtin_amdgcn_mfma_f32_16x16x16bf16_1k(
                        hi, pf[it][2 * q + 1], oacc[it][dt], 0, 0, 0);
                }
            }
        __builtin_amdgcn_s_setprio(0);
    }

    // full-wave softmax denominator for this j-half
    #pragma unroll
    for (int it = 0; it < 2; ++it) {
        lsum[it] += __shfl_xor(lsum[it], 16, 64);
        lsum[it] += __shfl_xor(lsum[it], 32, 64);
    }

    // combine the two j-halves (exactly additive under fixed-max softmax)
    if (wg == 0) {
        #pragma unroll
        for (int it = 0; it < 2; ++it) {
            int row = 32 * wi + 16 * it + l16;
            #pragma unroll
            for (int dt = 0; dt < 4; ++dt)
                *reinterpret_cast<float4v*>(&OLf[row * 68 + 16 * dt + 4 * g]) = oacc[it][dt];
            if (g == 0) lsumS[row] = lsum[it];
        }
    }
    __syncthreads();
    if (wg == 1) {
        #pragma unroll
        for (int it = 0; it < 2; ++it) {
            int row = 32 * wi + 16 * it + l16;
            float inv = 1.f / (lsumS[row] + lsum[it]);
            #pragma unroll
            for (int dt = 0; dt < 4; ++dt) {
                float4v o0 = *reinterpret_cast<const float4v*>(&OLf[row * 68 + 16 * dt + 4 * g]);
                #pragma unroll
                for (int r = 0; r < 4; ++r)
                    OLb[row * 72 + 16 * dt + 4 * g + r] =
                        f2bf((o0[r] + oacc[it][dt][r]) * inv);
            }
        }
    }
    __syncthreads();

    // coalesced store: O_T[pix][h*64+d]; 4 threads per row, 32B each
    {
        int row = tid >> 2, q4 = tid & 3;
        unsigned short* dst = oT + (((size_t)b << 10) + qb * 128 + row) * 256 + h * 64 + q4 * 16;
        const unsigned short* src = OLb + row * 72 + q4 * 16;
        *reinterpret_cast<uint4*>(dst)     = *reinterpret_cast<const uint4*>(src);
        *reinterpret_cast<uint4*>(dst + 8) = *reinterpret_cast<const uint4*>(src + 8);
    }
}

// ---------------------------------------------------------------------------
// Kernel 4: out projection + residual.  1D grid 1024, XCD-swizzled.
// ---------------------------------------------------------------------------
__global__ __launch_bounds__(256) void out_gemm(const unsigned short* __restrict__ oT,
                                                const unsigned short* __restrict__ wout,
                                                const float* __restrict__ x,
                                                float* __restrict__ out) {
    __shared__ __align__(16) unsigned short sW[8192];
    __shared__ __align__(16) unsigned short sX[8192];
    const int tid = threadIdx.x, lane = tid & 63, w = tid >> 6;
    const int l16 = lane & 15, g = lane >> 4;
    const int id = blockIdx.x;
    const int xcd = id & 7, sIdx = id >> 3;   // sIdx 0..127
    const int m = sIdx & 3, tq = sIdx >> 2;
    const int t = xcd + (tq << 3);
    const int pb = t & 15, b = t >> 4;

    const unsigned short* Wbase = wout + m * 64 * 256;
    const unsigned short* Xbase = oT + (((size_t)b << 10) + pb * 64) * 256;

    const int srow = (lane >> 3);
    const int sslot = lane & 7;

    auto stage = [&](int buf, int k0) {
        #pragma unroll
        for (int ii = 0; ii < 2; ++ii) {
            int inst = w + 4 * ii;
            int row = inst * 8 + srow;
            int src = row * 256 + k0 + 8 * (sslot ^ (row & 7));
            gload_lds16(Wbase + src, &sW[buf * 4096 + inst * 512]);
            gload_lds16(Xbase + src, &sX[buf * 4096 + inst * 512]);
        }
    };

    float4v acc[4] = {{0,0,0,0},{0,0,0,0},{0,0,0,0},{0,0,0,0}};
    stage(0, 0);
    __syncthreads();
    for (int ks = 0; ks < 4; ++ks) {
        if (ks < 3) stage((ks + 1) & 1, (ks + 1) * 64);
        const unsigned short* Wt = &sW[(ks & 1) * 4096];
        const unsigned short* Xt = &sX[(ks & 1) * 4096];
        #pragma unroll
        for (int kk = 0; kk < 2; ++kk) {
            bf16x8 aF = frag128(Wt, 16 * w + l16, 4 * kk + g);
            #pragma unroll
            for (int jt = 0; jt < 4; ++jt) {
                bf16x8 bF = frag128(Xt, 16 * jt + l16, 4 * kk + g);
                acc[jt] = mfma32(aF, bF, acc[jt]);
            }
        }
        __syncthreads();
    }

    #pragma unroll
    for (int jt = 0; jt < 4; ++jt)
        #pragma unroll
        for (int r = 0; r < 4; ++r) {
            size_t idx = ((size_t)b << 18) + (size_t)(m * 64 + 16 * w + 4 * g + r) * 1024
                       + pb * 64 + 16 * jt + l16;
            out[idx] = acc[jt][r] + x[idx];
        }
}

// ---------------------------------------------------------------------------
extern "C" void kernel_launch(void* const* d_in, const int* in_sizes, int n_in,
                              void* d_out, int out_size, void* d_ws, size_t ws_size,
                              hipStream_t stream) {
    const float* x  = (const float*)d_in[0];
    const float* g  = (const float*)d_in[1];
    const float* wq = (const float*)d_in[2];
    const float* wo = (const float*)d_in[3];
    float* out = (float*)d_out;

    char* ws = (char*)d_ws;
    // ws layout:
    //   [0, 8.4MB)        xn_T bf16 [16][1024][256]; reused as O_T after qkv_gemm
    //   [8.4, 16.8MB)     qhat bf16 [bh=64][1024][64]  (scaled by 8*log2e)
    //   [16.8, 25.2MB)    khat bf16 [bh=64][1024][64]
    //   [25.2, 33.6MB)    vperm bf16 [bh=64][16][64][64-permuted]
    //   [33.6MB, ...)     w_qkv bf16, w_out bf16
    unsigned short* xnT   = (unsigned short*)(ws);
    unsigned short* qhat  = (unsigned short*)(ws + 8388608);
    unsigned short* khat  = (unsigned short*)(ws + 16777216);
    unsigned short* vperm = (unsigned short*)(ws + 25165824);
    unsigned short* wqb   = (unsigned short*)(ws + 33554432);
    unsigned short* wob   = (unsigned short*)(ws + 33947648);
    unsigned short* oT    = xnT;   // reuse

    prep_kernel<<<1024, 256, 0, stream>>>(wq, wo, wqb, wob);
    ln_kernel<<<dim3(16, 16), 256, 0, stream>>>(x, g, xnT);
    qkv_gemm<<<3072, 256, 0, stream>>>(xnT, wqb, qhat, khat, vperm);
    attn_kernel<<<512, 512, 0, stream>>>(qhat, khat, vperm, oT);
    out_gemm<<<1024, 256, 0, stream>>>(oT, wob, x, out);
}

// Round 6
// 68.480 us; speedup vs baseline: 1.5389x; 1.5209x over previous
//
#include <hip/hip_runtime.h>
#include <hip/hip_bf16.h>

typedef short short4v __attribute__((ext_vector_type(4)));
typedef short short8v __attribute__((ext_vector_type(8)));
typedef float float4v __attribute__((ext_vector_type(4)));
typedef __bf16 bf16x8 __attribute__((ext_vector_type(8)));

typedef __attribute__((address_space(1))) const unsigned int g_uint;
typedef __attribute__((address_space(3))) unsigned int lds_uint;

__device__ __forceinline__ unsigned short f2bf(float f) {
    union { float f; unsigned int i; } t;
    t.f = f;
    unsigned int u = t.i;
    u += 0x7fffu + ((u >> 16) & 1u);   // round-to-nearest-even
    return (unsigned short)(u >> 16);
}

__device__ __forceinline__ short bfcast(float f) {
    __bf16 h = (__bf16)f;               // native cvt (compiler fuses pairs into v_cvt_pk_bf16_f32)
    return __builtin_bit_cast(short, h);
}

// v_exp_f32 computes 2^x; s_nop covers the trans->valu wait state
__device__ __forceinline__ float fast_exp2(float x) {
    float r;
    asm("v_exp_f32 %0, %1\n\ts_nop 0" : "=v"(r) : "v"(x));
    return r;
}

// async global->LDS, 16B per lane; lds dest is wave-uniform base + lane*16
__device__ __forceinline__ void gload_lds16(const unsigned short* g, unsigned short* l) {
    __builtin_amdgcn_global_load_lds((g_uint*)g, (lds_uint*)l, 16, 0, 0);
}

// read 8 contiguous bf16 (b128) from a swizzled [64][64] u16 tile:
// element (row, 8*slot + i) lives at u16 offset row*64 + ((slot ^ (row&7))<<3) + i
__device__ __forceinline__ bf16x8 frag128(const unsigned short* t, int row, int slot) {
    return *reinterpret_cast<const bf16x8*>(
        reinterpret_cast<const char*>(t) + row * 128 + (((slot ^ (row & 7)) << 4)));
}

__device__ __forceinline__ float4v mfma32(bf16x8 a, bf16x8 b, float4v c) {
    return __builtin_amdgcn_mfma_f32_16x16x32_bf16(a, b, c, 0, 0, 0);
}

// ---------------------------------------------------------------------------
// Kernel 0: weights f32 -> bf16
// ---------------------------------------------------------------------------
__global__ __launch_bounds__(256) void prep_kernel(const float* __restrict__ wq,
                                                   const float* __restrict__ wo,
                                                   unsigned short* __restrict__ wqb,
                                                   unsigned short* __restrict__ wob) {
    int i = blockIdx.x * 256 + threadIdx.x;   // 262144 total
    if (i < 196608) wqb[i] = f2bf(wq[i]);
    else            wob[i - 196608] = f2bf(wo[i - 196608]);
}

// ---------------------------------------------------------------------------
// Kernel 1: channel LayerNorm.  x[b][c=256][pix] f32 -> xn_T[b][pix][c] bf16.
// ---------------------------------------------------------------------------
__global__ __launch_bounds__(256) void ln_kernel(const float* __restrict__ x,
                                                 const float* __restrict__ g,
                                                 unsigned short* __restrict__ xnT) {
    __shared__ float red[2][4][64];
    const int tid = threadIdx.x;
    const int p = tid & 63, cg = tid >> 6;
    const int b = blockIdx.y;
    const int pix = blockIdx.x * 64 + p;
    const float* xb = x + ((size_t)b << 18) + pix;

    float v[64];
    float s = 0.f, q = 0.f;
    #pragma unroll
    for (int cc = 0; cc < 64; ++cc) {
        v[cc] = xb[(cg * 64 + cc) << 10];
        s += v[cc]; q += v[cc] * v[cc];
    }
    red[0][cg][p] = s; red[1][cg][p] = q;
    __syncthreads();
    float ts = red[0][0][p] + red[0][1][p] + red[0][2][p] + red[0][3][p];
    float tq = red[1][0][p] + red[1][1][p] + red[1][2][p] + red[1][3][p];
    float mean = ts * (1.f / 256.f);
    float var  = tq * (1.f / 256.f) - mean * mean;
    float rstd = rsqrtf(var + 1e-5f);
    float bias = -mean * rstd;

    unsigned short* dst = xnT + (((size_t)b << 10) + pix) * 256 + cg * 64;
    #pragma unroll
    for (int cc = 0; cc < 64; cc += 8) {
        union { uint4 u; unsigned short s[8]; } pk;
        #pragma unroll
        for (int j = 0; j < 8; ++j)
            pk.s[j] = f2bf(fmaf(v[cc + j], rstd, bias) * g[cg * 64 + cc + j]);
        *reinterpret_cast<uint4*>(dst + cc) = pk.u;
    }
}

// ---------------------------------------------------------------------------
// Kernel 2: QKV GEMM, fused L2-norm + attention-ready layouts.
// 1D grid 3072, XCD-swizzled so all 12 m-blocks of one X-tile share an XCD.
// m<4: qhat[bh][pix][d] (q * rn * 8*log2e)
// m 4..7: khatT swizzled tiles [bh][tile][j][d-swz]  (attn stages linearly)
// m>=8: vperm swizzled tiles [bh][tile][d][colperm-swz]
// ---------------------------------------------------------------------------
__global__ __launch_bounds__(256) void qkv_gemm(const unsigned short* __restrict__ xnT,
                                                const unsigned short* __restrict__ wqkv,
                                                unsigned short* __restrict__ qhat,
                                                unsigned short* __restrict__ khatT,
                                                unsigned short* __restrict__ vperm) {
    __shared__ __align__(16) unsigned short sW[8192];
    __shared__ __align__(16) unsigned short sX[8192];
    const int tid = threadIdx.x, lane = tid & 63, w = tid >> 6;
    const int l16 = lane & 15, g = lane >> 4;
    const int id = blockIdx.x;
    const int xcd = id & 7, sIdx = id >> 3;
    const int m = sIdx % 12, tq = sIdx / 12;
    const int t = xcd + (tq << 3);            // 0..255 X-tile index
    const int pb = t & 15, b = t >> 4;

    const unsigned short* Wbase = wqkv + m * 64 * 256;
    const unsigned short* Xbase = xnT + (((size_t)b << 10) + pb * 64) * 256;

    const int srow = (lane >> 3);
    const int sslot = lane & 7;

    auto stage = [&](int buf, int k0) {
        #pragma unroll
        for (int ii = 0; ii < 2; ++ii) {
            int inst = w + 4 * ii;
            int row = inst * 8 + srow;
            int src = row * 256 + k0 + 8 * (sslot ^ (row & 7));
            gload_lds16(Wbase + src, &sW[buf * 4096 + inst * 512]);
            gload_lds16(Xbase + src, &sX[buf * 4096 + inst * 512]);
        }
    };

    float4v acc[4] = {{0,0,0,0},{0,0,0,0},{0,0,0,0},{0,0,0,0}};
    const bool qk = (m < 8);

    stage(0, 0);
    __syncthreads();
    for (int ks = 0; ks < 4; ++ks) {
        if (ks < 3) stage((ks + 1) & 1, (ks + 1) * 64);
        const unsigned short* Wt = &sW[(ks & 1) * 4096];
        const unsigned short* Xt = &sX[(ks & 1) * 4096];
        #pragma unroll
        for (int kk = 0; kk < 2; ++kk) {
            bf16x8 aF = frag128(qk ? Xt : Wt, 16 * w + l16, 4 * kk + g);
            #pragma unroll
            for (int jt = 0; jt < 4; ++jt) {
                bf16x8 bF = frag128(qk ? Wt : Xt, 16 * jt + l16, 4 * kk + g);
                acc[jt] = mfma32(aF, bF, acc[jt]);
            }
        }
        __syncthreads();
    }

    if (qk) {
        // D[pix = pb*64 + 16w + 4g + r][d(head) = 16jt + l16]; l2-norm over d
        float rn[4];
        #pragma unroll
        for (int r = 0; r < 4; ++r) {
            float s = acc[0][r]*acc[0][r] + acc[1][r]*acc[1][r]
                    + acc[2][r]*acc[2][r] + acc[3][r]*acc[3][r];
            s += __shfl_xor(s, 1, 64);
            s += __shfl_xor(s, 2, 64);
            s += __shfl_xor(s, 4, 64);
            s += __shfl_xor(s, 8, 64);
            rn[r] = rsqrtf(fmaxf(s, 1e-24f));
        }
        int h = m & 3;
        int bh = b * 4 + h;
        if (m < 4) {
            // fold 8*log2(e) so attention can use p = exp2(st) with no bias
            unsigned short* qb = qhat + ((size_t)bh << 16) + (size_t)(pb * 64 + 16 * w) * 64;
            #pragma unroll
            for (int jt = 0; jt < 4; ++jt)
                #pragma unroll
                for (int r = 0; r < 4; ++r)
                    qb[(4 * g + r) * 64 + 16 * jt + l16] =
                        f2bf(acc[jt][r] * (rn[r] * 11.541560327111707f));
        } else {
            // swizzled K tile: element (j, d) at j*64 + ((d>>3 ^ (j&7))<<3) + (d&7)
            unsigned short* kb = khatT + ((size_t)(bh * 16 + pb)) * 4096;
            #pragma unroll
            for (int jt = 0; jt < 4; ++jt)
                #pragma unroll
                for (int r = 0; r < 4; ++r) {
                    int j = 16 * w + 4 * g + r;
                    int d = 16 * jt + l16;
                    kb[j * 64 + (((d >> 3) ^ (j & 7)) << 3) + (d & 7)] =
                        f2bf(acc[jt][r] * rn[r]);
                }
        }
    } else {
        // V tile [d][colperm(j)] with same XOR swizzle on the 16B slot
        int bh = b * 4 + (m - 8);
        unsigned short* vb = vperm + ((size_t)(bh * 16 + pb)) * 4096;
        #pragma unroll
        for (int jt = 0; jt < 4; ++jt) {
            int cphi = (l16 >> 2) * 2 + (jt >> 1);       // 16B-slot index of colperm(j)
            int cplo = (jt & 1) * 4 + (l16 & 3);         // position within slot
            #pragma unroll
            for (int r = 0; r < 4; ++r) {
                int d = 16 * w + 4 * g + r;
                vb[d * 64 + ((cphi ^ (d & 7)) << 3) + cplo] = f2bf(acc[jt][r]);
            }
        }
    }
}

// ---------------------------------------------------------------------------
// Kernel 3: flash attention, LDS double-buffered staging (T3 minimal 2-phase).
// grid 512 XCD-swizzled, 512 threads = 8 waves; each wave owns ONE 16-query
// i-tile (block = 128 queries).  K+V tile (16 KB) staged ONCE per block via
// global_load_lds w16 from pre-swizzled global tiles (linear copy); all
// fragment ds_read_b128 are <=2-way bank-aliased (free).
// Fixed-max softmax (q pre-scaled by 8*log2e): p = exp2(st), no rescale.
// ---------------------------------------------------------------------------
__global__ __launch_bounds__(512, 4) void attn_kernel(const unsigned short* __restrict__ qhat,
                                                      const unsigned short* __restrict__ khatT,
                                                      const unsigned short* __restrict__ vperm,
                                                      unsigned short* __restrict__ oT) {
    __shared__ __align__(16) unsigned short smem[16384];   // [buf][K 4096 | V 4096]
    const int tid = threadIdx.x, lane = tid & 63, w = tid >> 6;
    const int l16 = lane & 15, g = lane >> 4;
    const int id = blockIdx.x;
    const int sIdx = id >> 3;
    const int bh = (id & 7) * 8 + (sIdx >> 3);
    const int qb = sIdx & 7;
    const int b = bh >> 2, h = bh & 3;

    const unsigned short* Qg = qhat + ((size_t)bh << 16) + (size_t)(qb * 128) * 64;
    const unsigned short* Kt = khatT + ((size_t)(bh * 16)) * 4096;
    const unsigned short* Vt = vperm + ((size_t)(bh * 16)) * 4096;

    // Q fragment (B-operand of K=32 mfma): col i = l16 of this wave's i-tile
    bf16x8 bq[2];
    #pragma unroll
    for (int ds = 0; ds < 2; ++ds)
        bq[ds] = *reinterpret_cast<const bf16x8*>(
            Qg + (16 * w + l16) * 64 + 32 * ds + 8 * g);

    auto stage = [&](int buf, int t) {
        unsigned short* kb = &smem[buf * 8192 + w * 512];
        unsigned short* vb = &smem[buf * 8192 + 4096 + w * 512];
        gload_lds16(Kt + t * 4096 + w * 512 + lane * 8, kb);
        gload_lds16(Vt + t * 4096 + w * 512 + lane * 8, vb);
    };

    float lsum = 0.f;
    float4v oacc[4] = {};

    stage(0, 0);
    __syncthreads();

    for (int t = 0; t < 16; ++t) {
        const unsigned short* kb = &smem[(t & 1) * 8192];
        const unsigned short* vb = kb + 4096;
        if (t < 15) stage((t + 1) & 1, t + 1);   // issue next tile's loads early

        // S^T[j][i] = sum_d K[j][d] Q^T[d][i]
        float4v st[4] = {};
        #pragma unroll
        for (int ds = 0; ds < 2; ++ds) {
            bf16x8 ak[4];
            #pragma unroll
            for (int jt = 0; jt < 4; ++jt)
                ak[jt] = frag128(kb, 16 * jt + l16, 4 * ds + g);
            __builtin_amdgcn_s_setprio(1);
            #pragma unroll
            for (int jt = 0; jt < 4; ++jt)
                st[jt] = mfma32(ak[jt], bq[ds], st[jt]);
            __builtin_amdgcn_s_setprio(0);
        }

        // V fragment ds_reads issued before softmax; exp hides their latency
        short8v vv[4][2];
        #pragma unroll
        for (int dt = 0; dt < 4; ++dt) {
            int row = 16 * dt + l16;
            #pragma unroll
            for (int q = 0; q < 2; ++q)
                vv[dt][q] = *reinterpret_cast<const short8v*>(
                    reinterpret_cast<const char*>(vb) + row * 128 +
                    (((2 * g + q) ^ (row & 7)) << 4));
        }

        // fixed-max softmax: p = exp2(st)
        short4v pf[4];
        #pragma unroll
        for (int jt = 0; jt < 4; ++jt) {
            float p0 = fast_exp2(st[jt][0]);
            float p1 = fast_exp2(st[jt][1]);
            float p2 = fast_exp2(st[jt][2]);
            float p3 = fast_exp2(st[jt][3]);
            lsum += (p0 + p1) + (p2 + p3);
            short4v tt;
            tt[0] = bfcast(p0); tt[1] = bfcast(p1);
            tt[2] = bfcast(p2); tt[3] = bfcast(p3);
            pf[jt] = tt;
        }

        // O^T[d][i] += V^T[d][j] P^T[j][i]
        __builtin_amdgcn_s_setprio(1);
        #pragma unroll
        for (int dt = 0; dt < 4; ++dt)
            #pragma unroll
            for (int q = 0; q < 2; ++q) {
                short4v lo = __builtin_shufflevector(vv[dt][q], vv[dt][q], 0, 1, 2, 3);
                short4v hi = __builtin_shufflevector(vv[dt][q], vv[dt][q], 4, 5, 6, 7);
                oacc[dt] = __builtin_amdgcn_mfma_f32_16x16x16bf16_1k(
                    lo, pf[2 * q], oacc[dt], 0, 0, 0);
                oacc[dt] = __builtin_amdgcn_mfma_f32_16x16x16bf16_1k(
                    hi, pf[2 * q + 1], oacc[dt], 0, 0, 0);
            }
        __builtin_amdgcn_s_setprio(0);

        __syncthreads();   // buf consumed; next iter may overwrite it
    }

    // softmax denominator across the 4 lane-groups sharing column i
    lsum += __shfl_xor(lsum, 16, 64);
    lsum += __shfl_xor(lsum, 32, 64);
    float inv = 1.f / lsum;

    // transpose O through LDS (reuse smem) -> O_T[pix][h*64+d]
    unsigned short* OL = smem;   // [128][72] u16
    {
        int irow = 16 * w + l16;
        #pragma unroll
        for (int dt = 0; dt < 4; ++dt)
            #pragma unroll
            for (int r = 0; r < 4; ++r)
                OL[irow * 72 + 16 * dt + 4 * g + r] = f2bf(oacc[dt][r] * inv);
    }
    __syncthreads();
    {
        int row = tid >> 2, q4 = tid & 3;
        unsigned short* dst = oT + (((size_t)b << 10) + qb * 128 + row) * 256 + h * 64 + q4 * 16;
        const unsigned short* src = OL + row * 72 + q4 * 16;
        *reinterpret_cast<uint4*>(dst)     = *reinterpret_cast<const uint4*>(src);
        *reinterpret_cast<uint4*>(dst + 8) = *reinterpret_cast<const uint4*>(src + 8);
    }
}

// ---------------------------------------------------------------------------
// Kernel 4: out projection + residual.  1D grid 1024, XCD-swizzled.
// ---------------------------------------------------------------------------
__global__ __launch_bounds__(256) void out_gemm(const unsigned short* __restrict__ oT,
                                                const unsigned short* __restrict__ wout,
                                                const float* __restrict__ x,
                                                float* __restrict__ out) {
    __shared__ __align__(16) unsigned short sW[8192];
    __shared__ __align__(16) unsigned short sX[8192];
    const int tid = threadIdx.x, lane = tid & 63, w = tid >> 6;
    const int l16 = lane & 15, g = lane >> 4;
    const int id = blockIdx.x;
    const int xcd = id & 7, sIdx = id >> 3;   // sIdx 0..127
    const int m = sIdx & 3, tq = sIdx >> 2;
    const int t = xcd + (tq << 3);
    const int pb = t & 15, b = t >> 4;

    const unsigned short* Wbase = wout + m * 64 * 256;
    const unsigned short* Xbase = oT + (((size_t)b << 10) + pb * 64) * 256;

    const int srow = (lane >> 3);
    const int sslot = lane & 7;

    auto stage = [&](int buf, int k0) {
        #pragma unroll
        for (int ii = 0; ii < 2; ++ii) {
            int inst = w + 4 * ii;
            int row = inst * 8 + srow;
            int src = row * 256 + k0 + 8 * (sslot ^ (row & 7));
            gload_lds16(Wbase + src, &sW[buf * 4096 + inst * 512]);
            gload_lds16(Xbase + src, &sX[buf * 4096 + inst * 512]);
        }
    };

    float4v acc[4] = {{0,0,0,0},{0,0,0,0},{0,0,0,0},{0,0,0,0}};
    stage(0, 0);
    __syncthreads();
    for (int ks = 0; ks < 4; ++ks) {
        if (ks < 3) stage((ks + 1) & 1, (ks + 1) * 64);
        const unsigned short* Wt = &sW[(ks & 1) * 4096];
        const unsigned short* Xt = &sX[(ks & 1) * 4096];
        #pragma unroll
        for (int kk = 0; kk < 2; ++kk) {
            bf16x8 aF = frag128(Wt, 16 * w + l16, 4 * kk + g);
            #pragma unroll
            for (int jt = 0; jt < 4; ++jt) {
                bf16x8 bF = frag128(Xt, 16 * jt + l16, 4 * kk + g);
                acc[jt] = mfma32(aF, bF, acc[jt]);
            }
        }
        __syncthreads();
    }

    #pragma unroll
    for (int jt = 0; jt < 4; ++jt)
        #pragma unroll
        for (int r = 0; r < 4; ++r) {
            size_t idx = ((size_t)b << 18) + (size_t)(m * 64 + 16 * w + 4 * g + r) * 1024
                       + pb * 64 + 16 * jt + l16;
            out[idx] = acc[jt][r] + x[idx];
        }
}

// ---------------------------------------------------------------------------
extern "C" void kernel_launch(void* const* d_in, const int* in_sizes, int n_in,
                              void* d_out, int out_size, void* d_ws, size_t ws_size,
                              hipStream_t stream) {
    const float* x  = (const float*)d_in[0];
    const float* g  = (const float*)d_in[1];
    const float* wq = (const float*)d_in[2];
    const float* wo = (const float*)d_in[3];
    float* out = (float*)d_out;

    char* ws = (char*)d_ws;
    // ws layout:
    //   [0, 8.4MB)        xn_T bf16 [16][1024][256]; reused as O_T after qkv_gemm
    //   [8.4, 16.8MB)     qhat bf16 [bh=64][1024][64]  (scaled by 8*log2e)
    //   [16.8, 25.2MB)    khatT swizzled tiles [bh=64][16][64*64]
    //   [25.2, 33.6MB)    vperm swizzled tiles [bh=64][16][64*64]
    //   [33.6MB, ...)     w_qkv bf16, w_out bf16
    unsigned short* xnT   = (unsigned short*)(ws);
    unsigned short* qhat  = (unsigned short*)(ws + 8388608);
    unsigned short* khatT = (unsigned short*)(ws + 16777216);
    unsigned short* vperm = (unsigned short*)(ws + 25165824);
    unsigned short* wqb   = (unsigned short*)(ws + 33554432);
    unsigned short* wob   = (unsigned short*)(ws + 33947648);
    unsigned short* oT    = xnT;   // reuse

    prep_kernel<<<1024, 256, 0, stream>>>(wq, wo, wqb, wob);
    ln_kernel<<<dim3(16, 16), 256, 0, stream>>>(x, g, xnT);
    qkv_gemm<<<3072, 256, 0, stream>>>(xnT, wqb, qhat, khatT, vperm);
    attn_kernel<<<512, 512, 0, stream>>>(qhat, khatT, vperm, oT);
    out_gemm<<<1024, 256, 0, stream>>>(oT, wob, x, out);
}